// Round 9
// baseline (81.345 us; speedup 1.0000x reference)
//
#include <hip/hip_runtime.h>
#include <hip/hip_bf16.h>

// SPQR dequant-GEMV via MFMA: y = x @ Wd^T + CSR, M=N=8192, B=10, beta=16x16.
// R9: R8 with the bit_cast compile fix (memcpy — __hip_bfloat162 is not
//     trivially copyable on this ROCm). Packed bf16 converts
//     (v_cvt_pk_bf16_f32 via __float22bfloat162_rn), conflict-free padded
//     s/z LDS arrays, unroll-4 main loop.

constexpr int M_DIM = 8192;
constexpr int N_DIM = 8192;
constexpr int TN    = 512;              // N/16 scale groups per row
constexpr int BQ    = 10;               // batch (b*l)
constexpr int KSPLIT = 16;
constexpr int KRANGE = N_DIM / KSPLIT;  // 512
constexpr int KITERS = KRANGE / 32;     // 16 MFMA k-steps per wave
constexpr int RPB    = 64;              // rows per block (4 waves x 16)
constexpr int GPB    = KRANGE / 16;     // 32 scale groups per block k-range

typedef float  f32x4  __attribute__((ext_vector_type(4)));
typedef int    i32x4  __attribute__((ext_vector_type(4)));
typedef short  bf16x8 __attribute__((ext_vector_type(8)));

__device__ inline int pkbf(float a, float b) {     // -> v_cvt_pk_bf16_f32
    __hip_bfloat162 h = __float22bfloat162_rn(float2{a, b});
    int r;
    __builtin_memcpy(&r, &h, 4);
    return r;
}

__global__ __launch_bounds__(256, 4)
void spqr_mfma(const float* __restrict__ x,
               const int*   __restrict__ W,
               const int*   __restrict__ Ws,
               const int*   __restrict__ Wz,
               const float* __restrict__ Wss,
               const float* __restrict__ Wsz,
               const float* __restrict__ Wzs,
               const float* __restrict__ Wzz,
               float*       __restrict__ pws)
{
    __shared__ int   ldsA[KITERS * 64 * 4];        // 16KB: bf16 A-frags per k-iter/lane
    __shared__ float ldsS[RPB * 33];               // 8.4KB: s, +1-padded stride
    __shared__ float ldsZ[RPB * 33];               // 8.4KB: z

    const int t   = threadIdx.x;
    const int m0b = blockIdx.x * RPB;
    const int ks  = blockIdx.y;
    const int k0  = ks * KRANGE;
    const int g0  = k0 >> 4;

    // ---- stage A-fragments: lane l of k-iter kk holds x[b=l&15][k0+kk*32+(l>>4)*8 ..+7]
    for (int idx = t; idx < KITERS * 64; idx += 256) {
        const int kk = idx >> 6, l = idx & 63;
        const int b = l & 15, koff = (kk << 5) + ((l >> 4) << 3);
        int out[4] = {0, 0, 0, 0};
        if (b < BQ) {
            const float* xp = x + b * N_DIM + k0 + koff;
            f32x4 lo = *reinterpret_cast<const f32x4*>(xp);
            f32x4 hi = *reinterpret_cast<const f32x4*>(xp + 4);
            out[0] = pkbf(lo.x, lo.y);
            out[1] = pkbf(lo.z, lo.w);
            out[2] = pkbf(hi.x, hi.y);
            out[3] = pkbf(hi.z, hi.w);
        }
        *reinterpret_cast<i32x4*>(&ldsA[idx * 4]) = *reinterpret_cast<i32x4*>(out);
    }

    // ---- stage dequantized first-order (s,z) f32, padded conflict-free
    for (int idx = t; idx < RPB * GPB; idx += 256) {
        const int rl = idx >> 5;                   // local row 0..63
        const int gl = idx & 31;                   // local group 0..31
        const int m = m0b + rl, g = g0 + gl;
        const int tix = (m >> 4) * TN + g;
        ldsS[rl * 33 + gl] = ((float)Ws[m * TN + g] - Wsz[tix]) * Wss[tix];
        ldsZ[rl * 33 + gl] = ((float)Wz[m * TN + g] - Wzz[tix]) * Wzs[tix];
    }
    __syncthreads();

    // ---- main loop: stream W codes, dequant, MFMA ----
    const int wv = t >> 6, l = t & 63;
    const int lrow = l & 15;                       // tile row (W row offset / C col)
    const int lk   = l >> 4;                       // k-sub 0..3
    const int m0   = m0b + (wv << 4);
    const int* wp  = W + (size_t)(m0 + lrow) * N_DIM + k0 + (lk << 3);
    const int szrow = (wv << 4) + lrow;
    const int szk   = lk >> 1;                     // group offset within k-iter

    f32x4 acc = {0.f, 0.f, 0.f, 0.f};
    i32x4 cbufL[4], cbufH[4];                      // 3-deep rotating prefetch

    #pragma unroll
    for (int p = 0; p < 3; ++p) {
        cbufL[p] = *reinterpret_cast<const i32x4*>(wp + p * 32);
        cbufH[p] = *reinterpret_cast<const i32x4*>(wp + p * 32 + 4);
    }

    #pragma unroll 4
    for (int kk = 0; kk < KITERS; ++kk) {
        if (kk + 3 < KITERS) {
            cbufL[(kk + 3) & 3] = *reinterpret_cast<const i32x4*>(wp + (kk + 3) * 32);
            cbufH[(kk + 3) & 3] = *reinterpret_cast<const i32x4*>(wp + (kk + 3) * 32 + 4);
        }
        const i32x4 a4 = *reinterpret_cast<const i32x4*>(&ldsA[(kk * 64 + l) * 4]);
        const float s   = ldsS[szrow * 33 + kk * 2 + szk];
        const float z   = ldsZ[szrow * 33 + kk * 2 + szk];
        const float nzs = -z * s;                  // w = code*s + nzs
        const i32x4 cl = cbufL[kk & 3], ch = cbufH[kk & 3];
        int bw[4];
        bw[0] = pkbf(fmaf((float)cl.x, s, nzs), fmaf((float)cl.y, s, nzs));
        bw[1] = pkbf(fmaf((float)cl.z, s, nzs), fmaf((float)cl.w, s, nzs));
        bw[2] = pkbf(fmaf((float)ch.x, s, nzs), fmaf((float)ch.y, s, nzs));
        bw[3] = pkbf(fmaf((float)ch.z, s, nzs), fmaf((float)ch.w, s, nzs));
        const bf16x8 af = __builtin_bit_cast(bf16x8, a4);
        i32x4 bwv = *reinterpret_cast<i32x4*>(bw);
        const bf16x8 bf = __builtin_bit_cast(bf16x8, bwv);
        acc = __builtin_amdgcn_mfma_f32_16x16x32_bf16(af, bf, acc, 0, 0, 0);
    }

    // ---- store partials: C[row=b=(l>>4)*4+j][col=lrow] -> pws[ks][b][m0+lrow]
    float* pb = pws + (size_t)ks * (BQ * N_DIM) + (m0 + lrow);
    #pragma unroll
    for (int j = 0; j < 4; ++j) {
        const int b = (lk << 2) + j;
        if (b < BQ) pb[(size_t)b * N_DIM] = acc[j];
    }
}

__global__ __launch_bounds__(256, 4)
void spqr_reduce(const float* __restrict__ x,
                 const int*   __restrict__ row_offsets,
                 const int*   __restrict__ col_ids,
                 const float* __restrict__ values,
                 const float* __restrict__ pws,
                 float*       __restrict__ y)
{
    __shared__ float lsp[8][BQ];
    const int t  = threadIdx.x;
    const int m0 = blockIdx.x * 8;

    // CSR: 32 lanes per row, 8 rows
    {
        const int r = t >> 5, j = t & 31;
        const int m = m0 + r;
        const int base = row_offsets[m];
        const int cnt  = row_offsets[m + 1] - base;
        float c[BQ];
        #pragma unroll
        for (int b = 0; b < BQ; ++b) c[b] = 0.f;
        for (int jj = j; jj < cnt; jj += 32) {
            const int   col = col_ids[base + jj];
            const float v   = values[base + jj];
            #pragma unroll
            for (int b = 0; b < BQ; ++b)
                c[b] = fmaf(v, x[b * N_DIM + col], c[b]);
        }
        #pragma unroll
        for (int b = 0; b < BQ; ++b) {
            float v = c[b];
            for (int off = 16; off > 0; off >>= 1)
                v += __shfl_xor(v, off, 32);
            c[b] = v;
        }
        if (j == 0) {
            #pragma unroll
            for (int b = 0; b < BQ; ++b) lsp[r][b] = c[b];
        }
    }
    __syncthreads();

    if (t < 8 * BQ) {
        const int ml = t / BQ, b = t % BQ;
        const int m = m0 + ml;
        float v = lsp[ml][b];
        const float* pp = pws + (size_t)b * N_DIM + m;
        #pragma unroll
        for (int ksp = 0; ksp < KSPLIT; ++ksp)
            v += pp[(size_t)ksp * (BQ * N_DIM)];
        y[(size_t)b * M_DIM + m] = v;
    }
}

extern "C" void kernel_launch(void* const* d_in, const int* in_sizes, int n_in,
                              void* d_out, int out_size, void* d_ws, size_t ws_size,
                              hipStream_t stream)
{
    const float* x    = (const float*)d_in[0];
    const int*   W    = (const int*)  d_in[1];
    const int*   Ws   = (const int*)  d_in[2];
    const int*   Wz   = (const int*)  d_in[3];
    const float* Wss  = (const float*)d_in[4];
    const float* Wsz  = (const float*)d_in[5];
    const float* Wzs  = (const float*)d_in[6];
    const float* Wzz  = (const float*)d_in[7];
    const int*   roff = (const int*)  d_in[8];
    const int*   cids = (const int*)  d_in[9];
    const float* vals = (const float*)d_in[10];
    float* yout = (float*)d_out;
    float* pws  = (float*)d_ws;                   // 16 x 10 x 8192 f32 = 5.24 MB

    dim3 grid1(M_DIM / RPB, KSPLIT);              // 128 x 16 = 2048 blocks
    spqr_mfma<<<grid1, dim3(256), 0, stream>>>(x, W, Ws, Wz, Wss, Wsz, Wzs, Wzz, pws);

    dim3 grid2(M_DIM / 8);                        // 1024 blocks
    spqr_reduce<<<grid2, dim3(256), 0, stream>>>(x, roff, cids, vals, pws, yout);
}